// Round 1
// baseline (261.804 us; speedup 1.0000x reference)
//
#include <hip/hip_runtime.h>
#include <hip/hip_bf16.h>

#define B_ 16
#define L_ 4096
#define H_ 128
#define DM 11
#define LB 8
#define T_ (L_-LB)            /* 4088 */
#define TILE 64
#define P_ (TILE+LB)          /* 72 */
#define NT ((T_+TILE-1)/TILE) /* 64 */
#define EPSC 1e-6f

/* ws layout (floats):
   [0..3071]    : attn |delta| partials, 3 variants x 1024 blocks
   [3072..3199] : mags partials, 64 blocks x {vec,biv}
   [3200..3247] : qonly |delta|, 16 b x 3 variants
*/

__device__ __forceinline__ float phi_f(float a) { return (a >= 0.f ? a : 0.01f * a) + 1.f; }

__device__ __forceinline__ void ga_row(const float* __restrict__ x4, float sb,
                                       const float* __restrict__ vs, const float* __restrict__ vb,
                                       const float* __restrict__ bw, float* m) {
  float x0 = x4[0], x1 = x4[1], x2 = x4[2], x3 = x4[3];
  m[0]  = 1.f + sb;
  m[1]  = x0 * vs[0] + vb[0];
  m[2]  = x1 * vs[1] + vb[1];
  m[3]  = x2 * vs[2] + vb[2];
  m[4]  = x3 * vs[3] + vb[3];
  m[5]  = bw[0] * (x0 - x1);
  m[6]  = bw[1] * (x0 - x2);
  m[7]  = bw[2] * (x0 - x3);
  m[8]  = bw[3] * (x1 - x2);
  m[9]  = bw[4] * (x1 - x3);
  m[10] = bw[5] * (x2 - x3);
}

__global__ __launch_bounds__(256) void attn_kernel(
    const float* __restrict__ x, const float* __restrict__ sbp,
    const float* __restrict__ vs, const float* __restrict__ vb,
    const float* __restrict__ bw, const float* __restrict__ WQ,
    const float* __restrict__ WK, const float* __restrict__ WV,
    const float* __restrict__ hW, const float* __restrict__ hb,
    float* __restrict__ out, float* __restrict__ ws)
{
  __shared__ float sM[P_][DM];
  __shared__ float sMz[P_][DM];
  __shared__ float sWQ[DM][H_];
  __shared__ float sWK[DM][H_];
  __shared__ float sK[P_][H_];
  __shared__ float sU[P_];
  __shared__ float sWVe[DM];
  __shared__ float sPred[TILE];
  __shared__ float sRed[4];

  const int tid  = threadIdx.x;
  const int lane = tid & 63;
  const int wv   = tid >> 6;
  const int tile = blockIdx.x;
  const int b    = blockIdx.y;
  const int t_base = tile * TILE;

  // transpose-load WQ, WK into LDS: [d][h]
  for (int idx = tid; idx < DM * H_; idx += 256) {
    int d = idx >> 7, h = idx & (H_ - 1);
    sWQ[d][h] = WQ[h * DM + d];
    sWK[d][h] = WK[h * DM + d];
  }
  // wv_eff[d] = sum_g WV[g][d] * hW[g]
  if (tid < DM) {
    float a = 0.f;
    for (int g = 0; g < H_; ++g) a += WV[g * DM + tid] * hW[g];
    sWVe[tid] = a;
  }
  // M rows for this tile
  if (tid < P_) {
    int pos = t_base + tid;
    if (pos < L_) {
      ga_row(x + ((size_t)(b * L_ + pos)) * 4, sbp[0], vs, vb, bw, sM[tid]);
    } else {
      for (int d = 0; d < DM; ++d) sM[tid][d] = 0.f;
    }
  }
  const float hb0 = hb[0];
  float* out_pred = out;
  float* out_w    = out + (size_t)B_ * T_;

  for (int v = 0; v < 4; ++v) {
    __syncthreads();
    // masked M
    for (int idx = tid; idx < P_ * DM; idx += 256) {
      int rr = idx / DM, d = idx % DM;
      bool act = (v == 0) || (v == 1 && d != 0) || (v == 2 && (d == 0 || d >= 5)) || (v == 3 && d < 5);
      sMz[rr][d] = act ? sM[rr][d] : 0.f;
    }
    __syncthreads();
    // stage K = phi(Mz @ WK^T) and u = Mz . wv_eff
    for (int idx = tid; idx < P_ * H_; idx += 256) {
      int rr = idx >> 7, h = idx & (H_ - 1);
      float a = 0.f;
#pragma unroll
      for (int d = 0; d < DM; ++d) a += sMz[rr][d] * sWK[d][h];
      sK[rr][h] = phi_f(a);
    }
    if (tid < P_) {
      float a = 0.f;
#pragma unroll
      for (int d = 0; d < DM; ++d) a += sMz[tid][d] * sWVe[d];
      sU[tid] = a;
    }
    __syncthreads();

    float dsum = 0.f;
    for (int i = 0; i < TILE / 4; ++i) {
      int tt = wv * (TILE / 4) + i;
      int t  = t_base + tt;
      if (t >= T_) break;  // wave-uniform
      int qr = tt + LB;
      float a0 = 0.f, a1 = 0.f;
#pragma unroll
      for (int d = 0; d < DM; ++d) {
        float md = sMz[qr][d];
        a0 += md * sWQ[d][lane];
        a1 += md * sWQ[d][lane + 64];
      }
      float q0 = phi_f(a0), q1 = phi_f(a1);
      float s[LB];
#pragma unroll
      for (int l = 0; l < LB; ++l) {
        const float* kr = sK[tt + l];
        float p = q0 * kr[lane] + q1 * kr[lane + 64];
#pragma unroll
        for (int off = 32; off >= 1; off >>= 1) p += __shfl_xor(p, off);
        s[l] = p;
      }
      float den = EPSC, numu = 0.f;
#pragma unroll
      for (int l = 0; l < LB; ++l) { den += s[l]; numu += s[l] * sU[tt + l]; }
      float pred = hb0 + numu / den;
      if (v == 0) {
        if (lane == 0) {
          out_pred[(size_t)b * T_ + t] = pred;
          sPred[tt] = pred;
          float inv = 1.f / den;
          float4 w0 = make_float4(s[0] * inv, s[1] * inv, s[2] * inv, s[3] * inv);
          float4 w1 = make_float4(s[4] * inv, s[5] * inv, s[6] * inv, s[7] * inv);
          float4* wp = (float4*)(out_w + ((size_t)(b * T_ + t)) * 8);
          wp[0] = w0;
          wp[1] = w1;
        }
      } else {
        dsum += fabsf(sPred[tt] - pred);
      }
    }
    if (v > 0) {
      if (lane == 0) sRed[wv] = dsum;
      __syncthreads();
      if (tid == 0) {
        float tot = sRed[0] + sRed[1] + sRed[2] + sRed[3];
        ws[(size_t)(v - 1) * 1024 + (b * NT + tile)] = tot;
      }
    }
  }
}

__global__ __launch_bounds__(256) void mags_kernel(const float* __restrict__ x,
                                                   const float* __restrict__ vs,
                                                   const float* __restrict__ vb,
                                                   const float* __restrict__ bw,
                                                   float* __restrict__ ws)
{
  int gid = blockIdx.x * 256 + threadIdx.x;
  int stride = gridDim.x * 256;
  float sv = 0.f, sb2 = 0.f;
  for (int p = gid; p < B_ * L_; p += stride) {
    float4 xv = ((const float4*)x)[p];
    sv  += fabsf(xv.x * vs[0] + vb[0]) + fabsf(xv.y * vs[1] + vb[1]) +
           fabsf(xv.z * vs[2] + vb[2]) + fabsf(xv.w * vs[3] + vb[3]);
    sb2 += fabsf(bw[0] * (xv.x - xv.y)) + fabsf(bw[1] * (xv.x - xv.z)) +
           fabsf(bw[2] * (xv.x - xv.w)) + fabsf(bw[3] * (xv.y - xv.z)) +
           fabsf(bw[4] * (xv.y - xv.w)) + fabsf(bw[5] * (xv.z - xv.w));
  }
#pragma unroll
  for (int off = 32; off >= 1; off >>= 1) {
    sv  += __shfl_xor(sv, off);
    sb2 += __shfl_xor(sb2, off);
  }
  __shared__ float r[4][2];
  int lane = threadIdx.x & 63, w = threadIdx.x >> 6;
  if (lane == 0) { r[w][0] = sv; r[w][1] = sb2; }
  __syncthreads();
  if (threadIdx.x == 0) {
    ws[3072 + blockIdx.x * 2 + 0] = r[0][0] + r[1][0] + r[2][0] + r[3][0];
    ws[3072 + blockIdx.x * 2 + 1] = r[0][1] + r[1][1] + r[2][1] + r[3][1];
  }
}

__global__ __launch_bounds__(128) void qonly_kernel(
    const float* __restrict__ x, const float* __restrict__ sbp,
    const float* __restrict__ vs, const float* __restrict__ vb,
    const float* __restrict__ bw, const float* __restrict__ WQ,
    const float* __restrict__ WK, const float* __restrict__ WV,
    const float* __restrict__ hW, const float* __restrict__ hb,
    float* __restrict__ ws)
{
  const int b = blockIdx.x;
  const int tid = threadIdx.x, lane = tid & 63, w = tid >> 6;
  __shared__ float sMq[9][DM];
  __shared__ float sWVe[DM];
  __shared__ float sU[LB];
  __shared__ float red[2][LB];
  __shared__ float rmax[2][4];
  if (tid < 9) {
    int pos = (tid < 8) ? (L_ - 1 - LB + tid) : (L_ - 1);
    ga_row(x + ((size_t)(b * L_ + pos)) * 4, sbp[0], vs, vb, bw, sMq[tid]);
  }
  if (tid < DM) {
    float a = 0.f;
    for (int g = 0; g < H_; ++g) a += WV[g * DM + tid] * hW[g];
    sWVe[tid] = a;
  }
  __syncthreads();
  if (tid < LB) {
    float a = 0.f;
#pragma unroll
    for (int d = 0; d < DM; ++d) a += sMq[tid][d] * sWVe[d];
    sU[tid] = a;
  }
  __syncthreads();
  const int h = tid;
  const float* wq = WQ + h * DM;
  const float* wk = WK + h * DM;
  float q;
  {
    float a = 0.f;
#pragma unroll
    for (int d = 0; d < DM; ++d) a += sMq[8][d] * wq[d];
    q = phi_f(a);
  }
  float k[LB];
#pragma unroll
  for (int l = 0; l < LB; ++l) {
    float a = 0.f;
#pragma unroll
    for (int d = 0; d < DM; ++d) a += sMq[l][d] * wk[d];
    k[l] = phi_f(a);
  }
  float i0 = fabsf(wq[0]);
  float i1 = fabsf(wq[1]) + fabsf(wq[2]) + fabsf(wq[3]) + fabsf(wq[4]);
  float i2 = 0.f;
#pragma unroll
  for (int d = 5; d < 11; ++d) i2 += fabsf(wq[d]);
  float m0 = i0, m1 = i1, m2 = i2;
#pragma unroll
  for (int off = 32; off >= 1; off >>= 1) {
    m0 = fmaxf(m0, __shfl_xor(m0, off));
    m1 = fmaxf(m1, __shfl_xor(m1, off));
    m2 = fmaxf(m2, __shfl_xor(m2, off));
  }
  if (lane == 0) { rmax[w][0] = m0; rmax[w][1] = m1; rmax[w][2] = m2; }
  __syncthreads();
  m0 = fmaxf(rmax[0][0], rmax[1][0]);
  m1 = fmaxf(rmax[0][1], rmax[1][1]);
  m2 = fmaxf(rmax[0][2], rmax[1][2]);
  float hm0 = i0 / (m0 + 1e-12f), hm1 = i1 / (m1 + 1e-12f), hm2 = i2 / (m2 + 1e-12f);
  float qvs[4] = { q, q * (1.f - hm0), q * (1.f - hm1), q * (1.f - hm2) };
  float outs[4];
#pragma unroll
  for (int c = 0; c < 4; ++c) {
    float p[LB];
#pragma unroll
    for (int l = 0; l < LB; ++l) p[l] = qvs[c] * k[l];
#pragma unroll
    for (int off = 32; off >= 1; off >>= 1) {
#pragma unroll
      for (int l = 0; l < LB; ++l) p[l] += __shfl_xor(p[l], off);
    }
    if (lane == 0) {
#pragma unroll
      for (int l = 0; l < LB; ++l) red[w][l] = p[l];
    }
    __syncthreads();
    float num = 0.f, den = EPSC;
#pragma unroll
    for (int l = 0; l < LB; ++l) {
      float sl = red[0][l] + red[1][l];
      num += sl * sU[l];
      den += sl;
    }
    outs[c] = hb[0] + num / den;
    __syncthreads();
  }
  if (tid == 0) {
    ws[3200 + b * 3 + 0] = fabsf(outs[0] - outs[1]);
    ws[3200 + b * 3 + 1] = fabsf(outs[0] - outs[2]);
    ws[3200 + b * 3 + 2] = fabsf(outs[0] - outs[3]);
  }
}

__global__ __launch_bounds__(64) void finalize_kernel(const float* __restrict__ ws,
                                                      const float* __restrict__ sbp,
                                                      float* __restrict__ out)
{
  int lane = threadIdx.x;
  float s0 = 0.f, s1 = 0.f, s2 = 0.f, mv = 0.f, bv = 0.f;
  for (int i = lane; i < 1024; i += 64) {
    s0 += ws[i];
    s1 += ws[1024 + i];
    s2 += ws[2048 + i];
  }
  mv = ws[3072 + 2 * lane];
  bv = ws[3072 + 2 * lane + 1];
#pragma unroll
  for (int off = 32; off >= 1; off >>= 1) {
    s0 += __shfl_xor(s0, off);
    s1 += __shfl_xor(s1, off);
    s2 += __shfl_xor(s2, off);
    mv += __shfl_xor(mv, off);
    bv += __shfl_xor(bv, off);
  }
  if (lane == 0) {
    float q0 = 0.f, q1 = 0.f, q2 = 0.f;
    for (int b = 0; b < B_; ++b) {
      q0 += ws[3200 + b * 3 + 0];
      q1 += ws[3200 + b * 3 + 1];
      q2 += ws[3200 + b * 3 + 2];
    }
    float* oi = out + (size_t)B_ * T_ + (size_t)B_ * T_ * 8;
    const float inv_bt = 1.f / ((float)B_ * (float)T_);
    oi[0] = fabsf(1.f + sbp[0]);
    oi[1] = mv / ((float)B_ * (float)L_ * 4.f);
    oi[2] = bv / ((float)B_ * (float)L_ * 6.f);
    oi[3] = s0 * inv_bt;
    oi[4] = s1 * inv_bt;
    oi[5] = s2 * inv_bt;
    oi[6] = q0 / (float)B_;
    oi[7] = q1 / (float)B_;
    oi[8] = q2 / (float)B_;
  }
}

extern "C" void kernel_launch(void* const* d_in, const int* in_sizes, int n_in,
                              void* d_out, int out_size, void* d_ws, size_t ws_size,
                              hipStream_t stream) {
  (void)in_sizes; (void)n_in; (void)out_size; (void)ws_size;
  const float* x  = (const float*)d_in[0];
  const float* sb = (const float*)d_in[1];
  const float* vs = (const float*)d_in[2];
  const float* vb = (const float*)d_in[3];
  const float* bw = (const float*)d_in[4];
  const float* WQ = (const float*)d_in[5];
  const float* WK = (const float*)d_in[6];
  const float* WV = (const float*)d_in[7];
  const float* hW = (const float*)d_in[8];
  const float* hb = (const float*)d_in[9];
  float* out = (float*)d_out;
  float* ws  = (float*)d_ws;

  attn_kernel<<<dim3(NT, B_), 256, 0, stream>>>(x, sb, vs, vb, bw, WQ, WK, WV, hW, hb, out, ws);
  mags_kernel<<<64, 256, 0, stream>>>(x, vs, vb, bw, ws);
  qonly_kernel<<<B_, 128, 0, stream>>>(x, sb, vs, vb, bw, WQ, WK, WV, hW, hb, ws);
  finalize_kernel<<<1, 64, 0, stream>>>(ws, sb, out);
}

// Round 2
// 160.944 us; speedup vs baseline: 1.6267x; 1.6267x over previous
//
#include <hip/hip_runtime.h>

#define B_ 16
#define L_ 4096
#define H_ 128
#define DM 11
#define LB 8
#define T_ (L_-LB)            /* 4088 */
#define TT 256                /* t per block */
#define RR (TT+LB)            /* 264 rows staged */
#define CH 32                 /* h chunk */
#define NCH (H_/CH)           /* 4 */
#define NTB ((T_+TT-1)/TT)    /* 16 */
#define EPSC 1e-6f

/* ws layout (floats):
   [0..767]     : attn |delta| partials, 3 variants x 256 blocks
   [3072..3199] : mags partials, 64 blocks x {vec,biv}
   [3200..3247] : qonly |delta|, 16 b x 3 variants
*/

__device__ __forceinline__ float phi_f(float a) { return fmaxf(a, 0.01f * a) + 1.f; }

__device__ __forceinline__ void ld12(const float* __restrict__ p, float* __restrict__ o) {
  const float4* p4 = (const float4*)p;
  float4 a = p4[0], b = p4[1], c = p4[2];
  o[0]=a.x; o[1]=a.y; o[2]=a.z; o[3]=a.w;
  o[4]=b.x; o[5]=b.y; o[6]=b.z; o[7]=b.w;
  o[8]=c.x; o[9]=c.y; o[10]=c.z; o[11]=c.w;
}

/* variant-masked 11-dot: V0 all, V1 d>=1 (zero scalar), V2 d0+d5.. (zero vectors), V3 d0..4 (zero biv) */
template<int V>
__device__ __forceinline__ float dotv(const float* __restrict__ m, const float* __restrict__ w) {
  float a = 0.f;
  if (V == 0) {
#pragma unroll
    for (int d = 0; d < 11; ++d) a += m[d] * w[d];
  } else if (V == 1) {
#pragma unroll
    for (int d = 1; d < 11; ++d) a += m[d] * w[d];
  } else if (V == 2) {
    a = m[0] * w[0];
#pragma unroll
    for (int d = 5; d < 11; ++d) a += m[d] * w[d];
  } else {
#pragma unroll
    for (int d = 0; d < 5; ++d) a += m[d] * w[d];
  }
  return a;
}

__device__ __forceinline__ void ga_row(const float4 xv, float sb,
                                       const float* __restrict__ vs, const float* __restrict__ vb,
                                       const float* __restrict__ bw, float* m) {
  m[0]  = 1.f + sb;
  m[1]  = xv.x * vs[0] + vb[0];
  m[2]  = xv.y * vs[1] + vb[1];
  m[3]  = xv.z * vs[2] + vb[2];
  m[4]  = xv.w * vs[3] + vb[3];
  m[5]  = bw[0] * (xv.x - xv.y);
  m[6]  = bw[1] * (xv.x - xv.z);
  m[7]  = bw[2] * (xv.x - xv.w);
  m[8]  = bw[3] * (xv.y - xv.z);
  m[9]  = bw[4] * (xv.y - xv.w);
  m[10] = bw[5] * (xv.z - xv.w);
}

template<int V>
__device__ __forceinline__ void variant_pass(
    int tid, int w, int th, int ti, int hh, int r_s, int tl, int t, bool tvalid,
    int b, int tile,
    const float* __restrict__ mq, const float* __restrict__ ms, const float* __restrict__ m2,
    float (*sM)[12], float (*sWQT)[12], float (*sWKT)[12],
    float (*sK)[RR], float* sU, const float* sWVe, float* sRed,
    float hb0, float* __restrict__ out, float* __restrict__ ws, float& pred0)
{
  float s[LB] = {0.f,0.f,0.f,0.f,0.f,0.f,0.f,0.f};

  for (int c = 0; c < NCH; ++c) {
    __syncthreads();                       // prior readers of sK/sU done
    if (c == 0 && tid < RR) sU[tid] = dotv<V>(sM[tid], sWVe);
    // stage sK[hl][r] = phi(M[r] . WK[:,h]),  h = c*CH + hl ; thread owns row r_s, half hh
    {
#pragma unroll 4
      for (int j = 0; j < CH / 2; ++j) {
        int hl = hh * (CH / 2) + j;
        int h  = c * CH + hl;
        float wk[12]; ld12(sWKT[h], wk);
        sK[hl][r_s] = phi_f(dotv<V>(ms, wk));
      }
      if (r_s < RR - 256) {                // threads 0..15: rows 256..263
        int r2 = r_s + 256;
#pragma unroll 4
        for (int j = 0; j < CH / 2; ++j) {
          int hl = hh * (CH / 2) + j;
          int h  = c * CH + hl;
          float wk[12]; ld12(sWKT[h], wk);
          sK[hl][r2] = phi_f(dotv<V>(m2, wk));
        }
      }
    }
    __syncthreads();
    // score: lane owns t, half th of this chunk's h range
#pragma unroll 4
    for (int j = 0; j < CH / 2; ++j) {
      int hl = th * (CH / 2) + j;
      int h  = c * CH + hl;
      float wq[12]; ld12(sWQT[h], wq);
      float q = phi_f(dotv<V>(mq, wq));
      const float* kr = sK[hl];
#pragma unroll
      for (int l = 0; l < LB; ++l) s[l] += q * kr[tl + l];
    }
  }
  // merge h-halves (lane pairs i, i+32)
#pragma unroll
  for (int l = 0; l < LB; ++l) s[l] += __shfl_xor(s[l], 32);

  float den = EPSC, num = 0.f;
#pragma unroll
  for (int l = 0; l < LB; ++l) { den += s[l]; num += s[l] * sU[tl + l]; }
  float pred = hb0 + num / den;

  if (V == 0) {
    pred0 = pred;
    if (tvalid) {
      if (th == 0) out[(size_t)b * T_ + t] = pred;
      float inv = 1.f / den;
      int lo = th * 4;
      float4 wv4 = make_float4(s[lo] * inv, s[lo + 1] * inv, s[lo + 2] * inv, s[lo + 3] * inv);
      ((float4*)(out + (size_t)B_ * T_))[(size_t)(b * T_ + t) * 2 + th] = wv4;
    }
  } else {
    float dval = (tvalid && th == 0) ? fabsf(pred0 - pred) : 0.f;
#pragma unroll
    for (int off = 32; off >= 1; off >>= 1) dval += __shfl_xor(dval, off);
    if ((tid & 63) == 0) sRed[w] = dval;
    __syncthreads();
    if (tid == 0) {
      float tot = 0.f;
#pragma unroll
      for (int i = 0; i < 8; ++i) tot += sRed[i];
      ws[(V - 1) * 256 + b * NTB + tile] = tot;
    }
  }
}

__global__ __launch_bounds__(512) void attn_kernel(
    const float* __restrict__ x, const float* __restrict__ sbp,
    const float* __restrict__ vs, const float* __restrict__ vb,
    const float* __restrict__ bw, const float* __restrict__ WQ,
    const float* __restrict__ WK, const float* __restrict__ WV,
    const float* __restrict__ hW, const float* __restrict__ hb,
    float* __restrict__ out, float* __restrict__ ws)
{
  __shared__ __align__(16) float sM[RR][12];
  __shared__ __align__(16) float sWQT[H_][12];
  __shared__ __align__(16) float sWKT[H_][12];
  __shared__ float sK[CH][RR];
  __shared__ float sU[RR];
  __shared__ float sWVe[DM];
  __shared__ float sRed[8];

  const int tid  = threadIdx.x;
  const int lane = tid & 63;
  const int w    = tid >> 6;
  const int th   = lane >> 5;
  const int ti   = lane & 31;
  const int tile = blockIdx.x;
  const int b    = blockIdx.y;
  const int t_base = tile * TT;

  if (tid < H_) {
#pragma unroll
    for (int d = 0; d < DM; ++d) sWQT[tid][d] = WQ[tid * DM + d];
#pragma unroll
    for (int d = 0; d < DM; ++d) sWKT[tid][d] = WK[tid * DM + d];
  }
  if (tid >= 128 && tid < 128 + DM) {
    int d = tid - 128;
    float a = 0.f;
    for (int g = 0; g < H_; ++g) a += WV[g * DM + d] * hW[g];
    sWVe[d] = a;
  }
  if (tid < RR) {
    int pos = t_base + tid;
    if (pos < L_) {
      float4 xv = ((const float4*)x)[(size_t)b * L_ + pos];
      ga_row(xv, sbp[0], vs, vb, bw, sM[tid]);
    } else {
#pragma unroll
      for (int d = 0; d < DM; ++d) sM[tid][d] = 0.f;
    }
    sM[tid][11] = 0.f;
  }
  __syncthreads();

  const int tl = w * 32 + ti;       // local t index 0..255
  const int t  = t_base + tl;
  const bool tvalid = (t < T_);

  float mq[12]; ld12(sM[tl + 8], mq);       // q row
  const int r_s = tid >> 1;                 // staging row
  const int hh  = tid & 1;
  float ms[12]; ld12(sM[r_s], ms);
  float m2[12];
  if (r_s < RR - 256) ld12(sM[r_s + 256], m2);

  const float hb0 = hb[0];
  float pred0 = 0.f;

  variant_pass<0>(tid, w, th, ti, hh, r_s, tl, t, tvalid, b, tile, mq, ms, m2,
                  sM, sWQT, sWKT, sK, sU, sWVe, sRed, hb0, out, ws, pred0);
  variant_pass<1>(tid, w, th, ti, hh, r_s, tl, t, tvalid, b, tile, mq, ms, m2,
                  sM, sWQT, sWKT, sK, sU, sWVe, sRed, hb0, out, ws, pred0);
  variant_pass<2>(tid, w, th, ti, hh, r_s, tl, t, tvalid, b, tile, mq, ms, m2,
                  sM, sWQT, sWKT, sK, sU, sWVe, sRed, hb0, out, ws, pred0);
  variant_pass<3>(tid, w, th, ti, hh, r_s, tl, t, tvalid, b, tile, mq, ms, m2,
                  sM, sWQT, sWKT, sK, sU, sWVe, sRed, hb0, out, ws, pred0);
}

__global__ __launch_bounds__(256) void mags_kernel(const float* __restrict__ x,
                                                   const float* __restrict__ vs,
                                                   const float* __restrict__ vb,
                                                   const float* __restrict__ bw,
                                                   float* __restrict__ ws)
{
  int gid = blockIdx.x * 256 + threadIdx.x;
  int stride = gridDim.x * 256;
  float sv = 0.f, sb2 = 0.f;
  for (int p = gid; p < B_ * L_; p += stride) {
    float4 xv = ((const float4*)x)[p];
    sv  += fabsf(xv.x * vs[0] + vb[0]) + fabsf(xv.y * vs[1] + vb[1]) +
           fabsf(xv.z * vs[2] + vb[2]) + fabsf(xv.w * vs[3] + vb[3]);
    sb2 += fabsf(bw[0] * (xv.x - xv.y)) + fabsf(bw[1] * (xv.x - xv.z)) +
           fabsf(bw[2] * (xv.x - xv.w)) + fabsf(bw[3] * (xv.y - xv.z)) +
           fabsf(bw[4] * (xv.y - xv.w)) + fabsf(bw[5] * (xv.z - xv.w));
  }
#pragma unroll
  for (int off = 32; off >= 1; off >>= 1) {
    sv  += __shfl_xor(sv, off);
    sb2 += __shfl_xor(sb2, off);
  }
  __shared__ float r[4][2];
  int lane = threadIdx.x & 63, w = threadIdx.x >> 6;
  if (lane == 0) { r[w][0] = sv; r[w][1] = sb2; }
  __syncthreads();
  if (threadIdx.x == 0) {
    ws[3072 + blockIdx.x * 2 + 0] = r[0][0] + r[1][0] + r[2][0] + r[3][0];
    ws[3072 + blockIdx.x * 2 + 1] = r[0][1] + r[1][1] + r[2][1] + r[3][1];
  }
}

__global__ __launch_bounds__(128) void qonly_kernel(
    const float* __restrict__ x, const float* __restrict__ sbp,
    const float* __restrict__ vs, const float* __restrict__ vb,
    const float* __restrict__ bw, const float* __restrict__ WQ,
    const float* __restrict__ WK, const float* __restrict__ WV,
    const float* __restrict__ hW, const float* __restrict__ hb,
    float* __restrict__ ws)
{
  const int b = blockIdx.x;
  const int tid = threadIdx.x, lane = tid & 63, w = tid >> 6;
  __shared__ float sMq[9][DM];
  __shared__ float sWVe[DM];
  __shared__ float sU[LB];
  __shared__ float red[2][LB];
  __shared__ float rmax[2][4];
  if (tid < 9) {
    int pos = (tid < 8) ? (L_ - 1 - LB + tid) : (L_ - 1);
    float4 xv = ((const float4*)x)[(size_t)b * L_ + pos];
    ga_row(xv, sbp[0], vs, vb, bw, sMq[tid]);
  }
  if (tid < DM) {
    float a = 0.f;
    for (int g = 0; g < H_; ++g) a += WV[g * DM + tid] * hW[g];
    sWVe[tid] = a;
  }
  __syncthreads();
  if (tid < LB) {
    float a = 0.f;
#pragma unroll
    for (int d = 0; d < DM; ++d) a += sMq[tid][d] * sWVe[d];
    sU[tid] = a;
  }
  __syncthreads();
  const int h = tid;
  const float* wq = WQ + h * DM;
  const float* wk = WK + h * DM;
  float q;
  {
    float a = 0.f;
#pragma unroll
    for (int d = 0; d < DM; ++d) a += sMq[8][d] * wq[d];
    q = phi_f(a);
  }
  float k[LB];
#pragma unroll
  for (int l = 0; l < LB; ++l) {
    float a = 0.f;
#pragma unroll
    for (int d = 0; d < DM; ++d) a += sMq[l][d] * wk[d];
    k[l] = phi_f(a);
  }
  float i0 = fabsf(wq[0]);
  float i1 = fabsf(wq[1]) + fabsf(wq[2]) + fabsf(wq[3]) + fabsf(wq[4]);
  float i2 = 0.f;
#pragma unroll
  for (int d = 5; d < 11; ++d) i2 += fabsf(wq[d]);
  float m0 = i0, m1 = i1, m2 = i2;
#pragma unroll
  for (int off = 32; off >= 1; off >>= 1) {
    m0 = fmaxf(m0, __shfl_xor(m0, off));
    m1 = fmaxf(m1, __shfl_xor(m1, off));
    m2 = fmaxf(m2, __shfl_xor(m2, off));
  }
  if (lane == 0) { rmax[w][0] = m0; rmax[w][1] = m1; rmax[w][2] = m2; }
  __syncthreads();
  m0 = fmaxf(rmax[0][0], rmax[1][0]);
  m1 = fmaxf(rmax[0][1], rmax[1][1]);
  m2 = fmaxf(rmax[0][2], rmax[1][2]);
  float hm0 = i0 / (m0 + 1e-12f), hm1 = i1 / (m1 + 1e-12f), hm2 = i2 / (m2 + 1e-12f);
  float qvs[4] = { q, q * (1.f - hm0), q * (1.f - hm1), q * (1.f - hm2) };
  float outs[4];
#pragma unroll
  for (int c = 0; c < 4; ++c) {
    float p[LB];
#pragma unroll
    for (int l = 0; l < LB; ++l) p[l] = qvs[c] * k[l];
#pragma unroll
    for (int off = 32; off >= 1; off >>= 1) {
#pragma unroll
      for (int l = 0; l < LB; ++l) p[l] += __shfl_xor(p[l], off);
    }
    if (lane == 0) {
#pragma unroll
      for (int l = 0; l < LB; ++l) red[w][l] = p[l];
    }
    __syncthreads();
    float num = 0.f, den = EPSC;
#pragma unroll
    for (int l = 0; l < LB; ++l) {
      float sl = red[0][l] + red[1][l];
      num += sl * sU[l];
      den += sl;
    }
    outs[c] = hb[0] + num / den;
    __syncthreads();
  }
  if (tid == 0) {
    ws[3200 + b * 3 + 0] = fabsf(outs[0] - outs[1]);
    ws[3200 + b * 3 + 1] = fabsf(outs[0] - outs[2]);
    ws[3200 + b * 3 + 2] = fabsf(outs[0] - outs[3]);
  }
}

__global__ __launch_bounds__(64) void finalize_kernel(const float* __restrict__ ws,
                                                      const float* __restrict__ sbp,
                                                      float* __restrict__ out)
{
  int lane = threadIdx.x;
  float s0 = 0.f, s1 = 0.f, s2 = 0.f;
  for (int i = lane; i < 256; i += 64) {
    s0 += ws[i];
    s1 += ws[256 + i];
    s2 += ws[512 + i];
  }
  float mv = ws[3072 + 2 * lane];
  float bv = ws[3072 + 2 * lane + 1];
#pragma unroll
  for (int off = 32; off >= 1; off >>= 1) {
    s0 += __shfl_xor(s0, off);
    s1 += __shfl_xor(s1, off);
    s2 += __shfl_xor(s2, off);
    mv += __shfl_xor(mv, off);
    bv += __shfl_xor(bv, off);
  }
  if (lane == 0) {
    float q0 = 0.f, q1 = 0.f, q2 = 0.f;
    for (int b = 0; b < B_; ++b) {
      q0 += ws[3200 + b * 3 + 0];
      q1 += ws[3200 + b * 3 + 1];
      q2 += ws[3200 + b * 3 + 2];
    }
    float* oi = out + (size_t)B_ * T_ + (size_t)B_ * T_ * 8;
    const float inv_bt = 1.f / ((float)B_ * (float)T_);
    oi[0] = fabsf(1.f + sbp[0]);
    oi[1] = mv / ((float)B_ * (float)L_ * 4.f);
    oi[2] = bv / ((float)B_ * (float)L_ * 6.f);
    oi[3] = s0 * inv_bt;
    oi[4] = s1 * inv_bt;
    oi[5] = s2 * inv_bt;
    oi[6] = q0 / (float)B_;
    oi[7] = q1 / (float)B_;
    oi[8] = q2 / (float)B_;
  }
}

extern "C" void kernel_launch(void* const* d_in, const int* in_sizes, int n_in,
                              void* d_out, int out_size, void* d_ws, size_t ws_size,
                              hipStream_t stream) {
  (void)in_sizes; (void)n_in; (void)out_size; (void)ws_size;
  const float* x  = (const float*)d_in[0];
  const float* sb = (const float*)d_in[1];
  const float* vs = (const float*)d_in[2];
  const float* vb = (const float*)d_in[3];
  const float* bw = (const float*)d_in[4];
  const float* WQ = (const float*)d_in[5];
  const float* WK = (const float*)d_in[6];
  const float* WV = (const float*)d_in[7];
  const float* hW = (const float*)d_in[8];
  const float* hb = (const float*)d_in[9];
  float* out = (float*)d_out;
  float* ws  = (float*)d_ws;

  attn_kernel<<<dim3(NTB, B_), 512, 0, stream>>>(x, sb, vs, vb, bw, WQ, WK, WV, hW, hb, out, ws);
  mags_kernel<<<64, 256, 0, stream>>>(x, vs, vb, bw, ws);
  qonly_kernel<<<B_, 128, 0, stream>>>(x, sb, vs, vb, bw, WQ, WK, WV, hW, hb, ws);
  finalize_kernel<<<1, 64, 0, stream>>>(ws, sb, out);
}

// Round 3
// 74.238 us; speedup vs baseline: 3.5265x; 2.1679x over previous
//
#include <hip/hip_runtime.h>

#define B_ 16
#define L_ 4096
#define H_ 128
#define DM 11
#define LB 8
#define T_ (L_-LB)            /* 4088 */
#define TT 256                /* t per block, 1 per thread */
#define RR (TT+LB)            /* 264 rows */
#define CH 8                  /* h chunk */
#define CHP 9                 /* padded row stride (float4 units) */
#define NCH (H_/CH)           /* 16 */
#define NTB (L_/TT)           /* 16 tiles */
#define EPSC 1e-6f
#define MAGS_BASE 1024
#define QONLY_BASE 1600

/* ws layout (floats):
   [0..767]       attn |delta| partials, 3 variants x 256 blocks
   [1024..1535]   mags partials, 256 blocks x {vec,biv}
   [1600..1647]   qonly |delta|, 16 b x 3 variants
*/

__device__ __forceinline__ float phi_f(float a) { return fmaxf(a, 0.01f * a) + 1.f; }

__device__ __forceinline__ float4 phi4(float a, float b, float c, float d) {
  return make_float4(phi_f(a), phi_f(b), phi_f(c), phi_f(d));
}

/* r[0..3] = vector dims (M dims 1..4), r[4..9] = bivector dims (M dims 5..10) */
__device__ __forceinline__ void ga_parts(const float4 xv, const float* __restrict__ vs4,
                                         const float* __restrict__ vb4,
                                         const float* __restrict__ bw6, float* __restrict__ r) {
  r[0] = xv.x * vs4[0] + vb4[0];
  r[1] = xv.y * vs4[1] + vb4[1];
  r[2] = xv.z * vs4[2] + vb4[2];
  r[3] = xv.w * vs4[3] + vb4[3];
  r[4] = bw6[0] * (xv.x - xv.y);
  r[5] = bw6[1] * (xv.x - xv.z);
  r[6] = bw6[2] * (xv.x - xv.w);
  r[7] = bw6[3] * (xv.y - xv.z);
  r[8] = bw6[4] * (xv.y - xv.w);
  r[9] = bw6[5] * (xv.z - xv.w);
}

/* vec & biv partial dots against a 12-float weight row (w[0]=scalar, w[1..10]) */
__device__ __forceinline__ void dot2(const float* __restrict__ r, const float* __restrict__ w,
                                     float& dv, float& db) {
  dv = r[0] * w[1] + r[1] * w[2] + r[2] * w[3] + r[3] * w[4];
  db = r[4] * w[5] + r[5] * w[6] + r[6] * w[7] + r[7] * w[8] + r[8] * w[9] + r[9] * w[10];
}

__global__ __launch_bounds__(256) void attn_kernel(
    const float* __restrict__ x, const float* __restrict__ sbp,
    const float* __restrict__ vs, const float* __restrict__ vb,
    const float* __restrict__ bw, const float* __restrict__ WQ,
    const float* __restrict__ WK, const float* __restrict__ WV,
    const float* __restrict__ hW, const float* __restrict__ hb,
    float* __restrict__ out, float* __restrict__ ws)
{
  __shared__ float4 sK4[RR][CHP];       /* 38.0 KB: variant-packed K, padded stride */
  __shared__ float4 sU4[RR];            /* 4.2 KB */
  __shared__ __align__(16) float sWQ[H_][12];
  __shared__ __align__(16) float sWK[H_][12];
  __shared__ float sWVe[DM];
  __shared__ float sWVp[4][DM];
  __shared__ float sRed[4][8];

  const int tid  = threadIdx.x;
  const int lane = tid & 63;
  const int w    = tid >> 6;
  const int tile = blockIdx.x;
  const int b    = blockIdx.y;
  const int base = tile * TT;

  const float sb0 = sbp[0];
  const float m0c = 1.f + sb0;
  float vs4[4] = {vs[0], vs[1], vs[2], vs[3]};
  float vb4[4] = {vb[0], vb[1], vb[2], vb[3]};
  float bw6[6] = {bw[0], bw[1], bw[2], bw[3], bw[4], bw[5]};

  /* phase 1: weights to LDS + wve partials + own M rows to registers */
  if (tid < H_) {
#pragma unroll
    for (int d = 0; d < DM; ++d) sWQ[tid][d] = WQ[tid * DM + d];
    sWQ[tid][11] = 0.f;
#pragma unroll
    for (int d = 0; d < DM; ++d) sWK[tid][d] = WK[tid * DM + d];
    sWK[tid][11] = 0.f;
  } else if (tid < H_ + 44) {
    int idx = tid - H_;
    int d = idx % DM, p = idx / DM;
    float a = 0.f;
    for (int g = p * 32; g < p * 32 + 32; ++g) a += WV[g * DM + d] * hW[g];
    sWVp[p][d] = a;
  }

  float ms[10], mqv[10], m2v[10];
  {
    int rp = base + tid;                 /* always < L_ */
    float4 xv = ((const float4*)x)[(size_t)b * L_ + rp];
    ga_parts(xv, vs4, vb4, bw6, ms);
    int qp = base + tid + LB;
    if (qp < L_) {
      float4 xq = ((const float4*)x)[(size_t)b * L_ + qp];
      ga_parts(xq, vs4, vb4, bw6, mqv);
    } else {
#pragma unroll
      for (int i = 0; i < 10; ++i) mqv[i] = 0.f;
    }
    if (tid < LB) {
      int r2 = base + TT + tid;
      if (r2 < L_) {
        float4 x2 = ((const float4*)x)[(size_t)b * L_ + r2];
        ga_parts(x2, vs4, vb4, bw6, m2v);
      } else {
#pragma unroll
        for (int i = 0; i < 10; ++i) m2v[i] = 0.f;
      }
    }
  }
  float magv = fabsf(ms[0]) + fabsf(ms[1]) + fabsf(ms[2]) + fabsf(ms[3]);
  float magb = fabsf(ms[4]) + fabsf(ms[5]) + fabsf(ms[6]) + fabsf(ms[7]) + fabsf(ms[8]) + fabsf(ms[9]);

  __syncthreads();
  if (tid < DM) sWVe[tid] = sWVp[0][tid] + sWVp[1][tid] + sWVp[2][tid] + sWVp[3][tid];
  __syncthreads();

  /* u staging: variant-packed */
  {
    float wv[11];
#pragma unroll
    for (int i = 0; i < 11; ++i) wv[i] = sWVe[i];
    float uv, ub;
    dot2(ms, wv, uv, ub);               /* wv laid out like weight rows: wv[0] scalar */
    float c0 = m0c * wv[0];
    sU4[tid] = make_float4(c0 + uv + ub, uv + ub, c0 + ub, c0 + uv);
    if (tid < LB) {
      float uv2, ub2;
      dot2(m2v, wv, uv2, ub2);
      sU4[TT + tid] = make_float4(c0 + uv2 + ub2, uv2 + ub2, c0 + ub2, c0 + uv2);
    }
  }

  /* main loop: 16 chunks of 8 h */
  float4 s4[8];
#pragma unroll
  for (int l = 0; l < 8; ++l) s4[l] = make_float4(0.f, 0.f, 0.f, 0.f);

  for (int cc = 0; cc < NCH; ++cc) {
    __syncthreads();
    const int hbase = cc * CH;
#pragma unroll
    for (int hl = 0; hl < CH; ++hl) {
      const float* wk = sWK[hbase + hl];
      float dv, db;
      dot2(ms, wk, dv, db);
      float c0 = m0c * wk[0];
      float t1 = dv + db;
      sK4[tid][hl] = phi4(c0 + t1, t1, c0 + db, c0 + dv);
    }
    if (tid < LB) {
#pragma unroll
      for (int hl = 0; hl < CH; ++hl) {
        const float* wk = sWK[hbase + hl];
        float dv, db;
        dot2(m2v, wk, dv, db);
        float c0 = m0c * wk[0];
        float t1 = dv + db;
        sK4[TT + tid][hl] = phi4(c0 + t1, t1, c0 + db, c0 + dv);
      }
    }
    __syncthreads();
#pragma unroll
    for (int hl = 0; hl < CH; ++hl) {
      const float* wq = sWQ[hbase + hl];
      float dv, db;
      dot2(mqv, wq, dv, db);
      float c0 = m0c * wq[0];
      float t1 = dv + db;
      float4 q4 = phi4(c0 + t1, t1, c0 + db, c0 + dv);
#pragma unroll
      for (int l = 0; l < 8; ++l) {
        float4 k4 = sK4[tid + l][hl];
        s4[l].x += q4.x * k4.x;
        s4[l].y += q4.y * k4.y;
        s4[l].z += q4.z * k4.z;
        s4[l].w += q4.w * k4.w;
      }
    }
  }

  /* finish: den = sum of scores (== q.Z), num via u */
  float den0 = EPSC, den1 = EPSC, den2 = EPSC, den3 = EPSC;
  float num0 = 0.f, num1 = 0.f, num2 = 0.f, num3 = 0.f;
#pragma unroll
  for (int l = 0; l < 8; ++l) {
    float4 u4 = sU4[tid + l];
    den0 += s4[l].x; num0 += s4[l].x * u4.x;
    den1 += s4[l].y; num1 += s4[l].y * u4.y;
    den2 += s4[l].z; num2 += s4[l].z * u4.z;
    den3 += s4[l].w; num3 += s4[l].w * u4.w;
  }
  const float hb0 = hb[0];
  float p0 = hb0 + num0 / den0;
  float p1 = hb0 + num1 / den1;
  float p2 = hb0 + num2 / den2;
  float p3 = hb0 + num3 / den3;

  const int t = base + tid;
  const bool tvalid = (t < T_);
  if (tvalid) {
    out[(size_t)b * T_ + t] = p0;
    float inv = 1.f / den0;
    float4* wp = (float4*)(out + (size_t)B_ * T_ + ((size_t)b * T_ + t) * 8);
    wp[0] = make_float4(s4[0].x * inv, s4[1].x * inv, s4[2].x * inv, s4[3].x * inv);
    wp[1] = make_float4(s4[4].x * inv, s4[5].x * inv, s4[6].x * inv, s4[7].x * inv);
  }
  float d1 = tvalid ? fabsf(p0 - p1) : 0.f;
  float d2 = tvalid ? fabsf(p0 - p2) : 0.f;
  float d3 = tvalid ? fabsf(p0 - p3) : 0.f;
#pragma unroll
  for (int off = 32; off >= 1; off >>= 1) {
    d1 += __shfl_xor(d1, off);
    d2 += __shfl_xor(d2, off);
    d3 += __shfl_xor(d3, off);
    magv += __shfl_xor(magv, off);
    magb += __shfl_xor(magb, off);
  }
  if (lane == 0) {
    sRed[w][0] = d1; sRed[w][1] = d2; sRed[w][2] = d3; sRed[w][3] = magv; sRed[w][4] = magb;
  }
  __syncthreads();
  if (tid == 0) {
    int bid = b * NTB + tile;
    float t1 = 0.f, t2 = 0.f, t3 = 0.f, tm = 0.f, tb2 = 0.f;
#pragma unroll
    for (int i = 0; i < 4; ++i) {
      t1 += sRed[i][0]; t2 += sRed[i][1]; t3 += sRed[i][2]; tm += sRed[i][3]; tb2 += sRed[i][4];
    }
    ws[bid]         = t1;
    ws[256 + bid]   = t2;
    ws[512 + bid]   = t3;
    ws[MAGS_BASE + 2 * bid]     = tm;
    ws[MAGS_BASE + 2 * bid + 1] = tb2;
  }

  /* qonly fused into tile 15, wave 0 (barrier-free, intra-wave) */
  if (tile == NTB - 1 && tid < 64) {
    const int h0 = tid, h1 = tid + 64;
    float wq0[11], wq1[11], wk0[11], wk1[11], wv[11];
#pragma unroll
    for (int d = 0; d < DM; ++d) {
      wq0[d] = sWQ[h0][d]; wq1[d] = sWQ[h1][d];
      wk0[d] = sWK[h0][d]; wk1[d] = sWK[h1][d];
      wv[d]  = sWVe[d];
    }
    float A0 = 0.f, Z0 = 0.f, A1 = 0.f, Z1 = 0.f;
#pragma unroll
    for (int l = 0; l < LB; ++l) {
      float4 xv = ((const float4*)x)[(size_t)b * L_ + (L_ - 1 - LB + l)];
      float r[10];
      ga_parts(xv, vs4, vb4, bw6, r);
      float uv, ub;
      dot2(r, wv, uv, ub);
      float u = m0c * wv[0] + uv + ub;
      float dv, db;
      dot2(r, wk0, dv, db);
      float k0 = phi_f(m0c * wk0[0] + dv + db);
      dot2(r, wk1, dv, db);
      float k1 = phi_f(m0c * wk1[0] + dv + db);
      A0 += k0 * u; Z0 += k0;
      A1 += k1 * u; Z1 += k1;
    }
    float q0, q1;
    {
      float4 xv = ((const float4*)x)[(size_t)b * L_ + (L_ - 1)];
      float r[10];
      ga_parts(xv, vs4, vb4, bw6, r);
      float dv, db;
      dot2(r, wq0, dv, db);
      q0 = phi_f(m0c * wq0[0] + dv + db);
      dot2(r, wq1, dv, db);
      q1 = phi_f(m0c * wq1[0] + dv + db);
    }
    float i00 = fabsf(wq0[0]);
    float i01 = fabsf(wq0[1]) + fabsf(wq0[2]) + fabsf(wq0[3]) + fabsf(wq0[4]);
    float i02 = fabsf(wq0[5]) + fabsf(wq0[6]) + fabsf(wq0[7]) + fabsf(wq0[8]) + fabsf(wq0[9]) + fabsf(wq0[10]);
    float i10 = fabsf(wq1[0]);
    float i11 = fabsf(wq1[1]) + fabsf(wq1[2]) + fabsf(wq1[3]) + fabsf(wq1[4]);
    float i12 = fabsf(wq1[5]) + fabsf(wq1[6]) + fabsf(wq1[7]) + fabsf(wq1[8]) + fabsf(wq1[9]) + fabsf(wq1[10]);
    float mm0 = fmaxf(i00, i10), mm1 = fmaxf(i01, i11), mm2 = fmaxf(i02, i12);
#pragma unroll
    for (int off = 32; off >= 1; off >>= 1) {
      mm0 = fmaxf(mm0, __shfl_xor(mm0, off));
      mm1 = fmaxf(mm1, __shfl_xor(mm1, off));
      mm2 = fmaxf(mm2, __shfl_xor(mm2, off));
    }
    mm0 += 1e-12f; mm1 += 1e-12f; mm2 += 1e-12f;
    float qa[4], qb_[4];
    qa[0] = q0;                      qb_[0] = q1;
    qa[1] = q0 * (1.f - i00 / mm0);  qb_[1] = q1 * (1.f - i10 / mm0);
    qa[2] = q0 * (1.f - i01 / mm1);  qb_[2] = q1 * (1.f - i11 / mm1);
    qa[3] = q0 * (1.f - i02 / mm2);  qb_[3] = q1 * (1.f - i12 / mm2);
    float num[4], den[4];
#pragma unroll
    for (int c = 0; c < 4; ++c) {
      num[c] = qa[c] * A0 + qb_[c] * A1;
      den[c] = qa[c] * Z0 + qb_[c] * Z1;
    }
#pragma unroll
    for (int off = 32; off >= 1; off >>= 1) {
#pragma unroll
      for (int c = 0; c < 4; ++c) {
        num[c] += __shfl_xor(num[c], off);
        den[c] += __shfl_xor(den[c], off);
      }
    }
    if (tid == 0) {
      float o0 = hb0 + num[0] / (den[0] + EPSC);
      float o1 = hb0 + num[1] / (den[1] + EPSC);
      float o2 = hb0 + num[2] / (den[2] + EPSC);
      float o3 = hb0 + num[3] / (den[3] + EPSC);
      ws[QONLY_BASE + b * 3 + 0] = fabsf(o0 - o1);
      ws[QONLY_BASE + b * 3 + 1] = fabsf(o0 - o2);
      ws[QONLY_BASE + b * 3 + 2] = fabsf(o0 - o3);
    }
  }
}

__global__ __launch_bounds__(64) void finalize_kernel(const float* __restrict__ ws,
                                                      const float* __restrict__ sbp,
                                                      float* __restrict__ out)
{
  int lane = threadIdx.x;
  float s0 = 0.f, s1 = 0.f, s2 = 0.f, mv = 0.f, bv = 0.f;
  for (int i = lane; i < 256; i += 64) {
    s0 += ws[i];
    s1 += ws[256 + i];
    s2 += ws[512 + i];
    mv += ws[MAGS_BASE + 2 * i];
    bv += ws[MAGS_BASE + 2 * i + 1];
  }
#pragma unroll
  for (int off = 32; off >= 1; off >>= 1) {
    s0 += __shfl_xor(s0, off);
    s1 += __shfl_xor(s1, off);
    s2 += __shfl_xor(s2, off);
    mv += __shfl_xor(mv, off);
    bv += __shfl_xor(bv, off);
  }
  if (lane == 0) {
    float q0 = 0.f, q1 = 0.f, q2 = 0.f;
    for (int b = 0; b < B_; ++b) {
      q0 += ws[QONLY_BASE + b * 3 + 0];
      q1 += ws[QONLY_BASE + b * 3 + 1];
      q2 += ws[QONLY_BASE + b * 3 + 2];
    }
    float* oi = out + (size_t)B_ * T_ + (size_t)B_ * T_ * 8;
    const float inv_bt = 1.f / ((float)B_ * (float)T_);
    oi[0] = fabsf(1.f + sbp[0]);
    oi[1] = mv / ((float)B_ * (float)L_ * 4.f);
    oi[2] = bv / ((float)B_ * (float)L_ * 6.f);
    oi[3] = s0 * inv_bt;
    oi[4] = s1 * inv_bt;
    oi[5] = s2 * inv_bt;
    oi[6] = q0 / (float)B_;
    oi[7] = q1 / (float)B_;
    oi[8] = q2 / (float)B_;
  }
}

extern "C" void kernel_launch(void* const* d_in, const int* in_sizes, int n_in,
                              void* d_out, int out_size, void* d_ws, size_t ws_size,
                              hipStream_t stream) {
  (void)in_sizes; (void)n_in; (void)out_size; (void)ws_size;
  const float* x  = (const float*)d_in[0];
  const float* sb = (const float*)d_in[1];
  const float* vs = (const float*)d_in[2];
  const float* vb = (const float*)d_in[3];
  const float* bw = (const float*)d_in[4];
  const float* WQ = (const float*)d_in[5];
  const float* WK = (const float*)d_in[6];
  const float* WV = (const float*)d_in[7];
  const float* hW = (const float*)d_in[8];
  const float* hb = (const float*)d_in[9];
  float* out = (float*)d_out;
  float* ws  = (float*)d_ws;

  attn_kernel<<<dim3(NTB, B_), 256, 0, stream>>>(x, sb, vs, vb, bw, WQ, WK, WV, hW, hb, out, ws);
  finalize_kernel<<<1, 64, 0, stream>>>(ws, sb, out);
}